// Round 14
// baseline (685.249 us; speedup 1.0000x reference)
//
#include <hip/hip_runtime.h>
#include <hip/hip_bf16.h>
#include <cstdint>

// Problem constants (fixed by the reference)
constexpr int  KDIM  = 4096;    // D_IN
constexpr int  NDIM  = 4096;    // D_OUT
constexpr long MDIM  = 16384;   // B*S
constexpr int  RANK_ = 16;
constexpr float SCALE_ = 2.0f;  // alpha/rank

constexpr int BK = 32;
constexpr int NT = KDIM / BK;   // 128 K-tiles
constexpr int BUFB = 24576;     // bytes per LDS K-tile buffer (B 16K + A 8K)

using bf16x8 = __attribute__((ext_vector_type(8))) short;
using f32x4  = __attribute__((ext_vector_type(4))) float;

__device__ __forceinline__ void gload_lds16(const void* g, void* l) {
  __builtin_amdgcn_global_load_lds(
      (const __attribute__((address_space(1))) void*)g,
      (__attribute__((address_space(3))) void*)l, 16, 0, 0);
}

__device__ __forceinline__ unsigned short f2bf(float f) {
  union { float f; unsigned u; } v; v.f = f;
  unsigned r = v.u + 0x7FFFu + ((v.u >> 16) & 1u);
  return (unsigned short)(r >> 16);
}

#define LDF(P, OFF) (*reinterpret_cast<const bf16x8*>((P) + (OFF)))

// ---------------------------------------------------------------------------
// Kernel 1 (fused prologue, R13-proven): blocks [0,512) build Wp; rest conv x.
// ---------------------------------------------------------------------------
__global__ __launch_bounds__(256) void fused_prep_kernel(
    const float* __restrict__ x,  const float* __restrict__ W,
    const float* __restrict__ lA, const float* __restrict__ lB,
    unsigned short* __restrict__ xb, unsigned short* __restrict__ Wp) {
  if (blockIdx.x < 512) {
    const long totW = (long)NDIM * KDIM / 8;
    for (long t = blockIdx.x * 256L + threadIdx.x; t < totW; t += 512L * 256) {
      const int o  = (int)(t / (KDIM / 8));
      const int d8 = (int)(t % (KDIM / 8)) * 8;
      const float4* w4 = reinterpret_cast<const float4*>(W + (size_t)o * KDIM + d8);
      float4 w0 = w4[0], w1 = w4[1];
      float acc[8] = {w0.x, w0.y, w0.z, w0.w, w1.x, w1.y, w1.z, w1.w};
#pragma unroll
      for (int r = 0; r < RANK_; ++r) {
        const float br = SCALE_ * lB[o * RANK_ + r];
        const float4* a4 = reinterpret_cast<const float4*>(lA + (size_t)r * KDIM + d8);
        float4 a0 = a4[0], a1 = a4[1];
        acc[0] += br * a0.x; acc[1] += br * a0.y; acc[2] += br * a0.z; acc[3] += br * a0.w;
        acc[4] += br * a1.x; acc[5] += br * a1.y; acc[6] += br * a1.z; acc[7] += br * a1.w;
      }
      uint4 o4;
      o4.x = (unsigned)f2bf(acc[0]) | ((unsigned)f2bf(acc[1]) << 16);
      o4.y = (unsigned)f2bf(acc[2]) | ((unsigned)f2bf(acc[3]) << 16);
      o4.z = (unsigned)f2bf(acc[4]) | ((unsigned)f2bf(acc[5]) << 16);
      o4.w = (unsigned)f2bf(acc[6]) | ((unsigned)f2bf(acc[7]) << 16);
      *reinterpret_cast<uint4*>(Wp + t * 8) = o4;
    }
  } else {
    const long totX = MDIM * KDIM / 8;
    for (long t = (blockIdx.x - 512) * 256L + threadIdx.x; t < totX;
         t += 3584L * 256) {
      const float4* p = reinterpret_cast<const float4*>(x + t * 8);
      float4 a = p[0], b = p[1];
      uint4 o4;
      o4.x = (unsigned)f2bf(a.x) | ((unsigned)f2bf(a.y) << 16);
      o4.y = (unsigned)f2bf(a.z) | ((unsigned)f2bf(a.w) << 16);
      o4.z = (unsigned)f2bf(b.x) | ((unsigned)f2bf(b.y) << 16);
      o4.w = (unsigned)f2bf(b.z) | ((unsigned)f2bf(b.w) << 16);
      *reinterpret_cast<uint4*>(xb + t * 8) = o4;
    }
  }
}

// ---------------------------------------------------------------------------
// Kernel 2: 128x256 tile, BK=32, 8 waves of 64x64 output, 2-PHASE/K-tile.
//   Sized for 2 BLOCKS/CU: LDS 48KB/block, VGPR budget <=128/wave (acc 64 +
//   frags 32 + addr) -> 4 waves/SIMD. Cross-block overlap hides the barrier/
//   vmcnt convoys that capped the 1-block/CU design at MfmaUtil 54.5.
//   Buffer layout per 24KB buf: B [256 rows][64B] @0, A [128 rows][64B] @16K.
//   Loads/K-tile/wave = 3 (A 1, B 2). FIFO: entering P1(t): {A(t+1), B(t+1)x2}.
//     P1(t): read w23(t)(2); stage A(t+2)(1); Q0 = 4m x n01 (x,w01 from
//            prev P2); vmcnt(1) -> retires ALL of t+1, leaves A(t+2); bar
//     P2(t): read w01(t+1)(2); stage B(t+2)(2); Q1 = 4m x n23;
//            read x(t+1)(4) after Q1 (WAR); bar
//   Write-after-read gaps: 1 barrier + LDS-pipe in-order + >=200cyc gload
//   return latency (same argument as m201 template). Tails: vmcnt(0)@NT-2.
// ---------------------------------------------------------------------------
__global__ __launch_bounds__(512, 4) void gemm128_kernel(
    const unsigned short* __restrict__ A,   // [MDIM][KDIM] bf16 bits (x)
    const unsigned short* __restrict__ Bm,  // [NDIM][KDIM] bf16 bits (W')
    const float* __restrict__ bias,
    float* __restrict__ C) {
  __shared__ __align__(16) unsigned char lds[2 * BUFB];

  const int tid  = threadIdx.x;
  const int wave = tid >> 6, lane = tid & 63;
  const int wm = wave >> 2, wn = wave & 3;       // 2 x 4 wave grid (64x64 each)
  const int r16 = lane & 15, hi = lane >> 4;
  const int swz5 = ((r16 >> 3) & 1) << 5;        // verified-0-conflict swizzle

  // XCD-aware bijective blockIdx swizzle (nwg = 2048, 2048 % 8 == 0)
  const int orig = blockIdx.x;
  const int bid  = (orig & 7) * 256 + (orig >> 3);
  const int bcol = (bid & 15) * 256;             // N-tile (16 cols)
  const int brow = (bid >> 4) * 128;             // M-tile (128 rows)

  // staging: linear LDS dest + inverse-swizzled source (verified family)
  const int st_col = ((lane & 3) * 8) ^ (((lane >> 5) & 1) << 4);
  const unsigned short* AsrcS =
      A  + (size_t)(brow + wave * 16 + (lane >> 2)) * KDIM + st_col;
  const unsigned short* BsrcS =
      Bm + (size_t)(bcol + wave * 32 + (lane >> 2)) * KDIM + st_col;

  auto stageA = [&](unsigned char* base, int tau) {   // 1 gload: 128x32 A
    gload_lds16(AsrcS + (size_t)tau * BK, base + 16384 + (wave << 10));
  };
  auto stageB = [&](unsigned char* base, int tau) {   // 2 gloads: 256x32 B
    const unsigned short* g = BsrcS + (size_t)tau * BK;
    unsigned char* d = base + (wave << 11);
    gload_lds16(g,                      d);
    gload_lds16(g + (size_t)16 * KDIM,  d + 1024);
  };

  // per-lane read bases; fragment = base + const offset (1024 per 16 rows)
  const int laneoff = r16 * 64 + ((hi * 16) ^ swz5);
  const unsigned char* pB0 = lds + wn * 4096 + laneoff;
  const unsigned char* pA0 = lds + 16384 + wm * 4096 + laneoff;
  const unsigned char* pB1 = pB0 + BUFB;
  const unsigned char* pA1 = pA0 + BUFB;

  f32x4 acc[4][4];
#pragma unroll
  for (int m = 0; m < 4; ++m)
#pragma unroll
    for (int n = 0; n < 4; ++n) acc[m][n] = (f32x4){0.f, 0.f, 0.f, 0.f};

  unsigned char* const buf0 = lds;
  unsigned char* const buf1 = lds + BUFB;

  // prologue: tiles 0,1 staged (6 loads); vmcnt(3) retires tile0 exactly,
  // leaving {A(1), B(1)x2} = steady-state invariant entering P1(0).
  stageA(buf0, 0); stageB(buf0, 0);
  stageA(buf1, 1); stageB(buf1, 1);
  asm volatile("s_waitcnt vmcnt(3)" ::: "memory");
  __builtin_amdgcn_s_barrier();

  bf16x8 x[4], w[4];
  // boundary pre-reads for tile 0 (the P2(-1) reads): x(0), w01(0)
#pragma unroll
  for (int m = 0; m < 4; ++m) x[m] = LDF(pA0, m * 1024);
  w[0] = LDF(pB0, 0);
  w[1] = LDF(pB0, 1024);

  // One K-tile. PA/PB = cur bases, PAN/PBN = next, CB = cur staging buffer
  // (buf(t+2) has same parity as t).
#define KTILE(PA, PB, PAN, PBN, CB, t)                                         \
  {                                                                            \
    /* P1: read w23(t); stage A(t+2); Q0 = 4m x n01; vmcnt(1); bar */          \
    w[2] = LDF(PB, 2 * 1024);                                                  \
    w[3] = LDF(PB, 3 * 1024);                                                  \
    if ((t) + 2 < NT) stageA((CB), (t) + 2);                                   \
    __builtin_amdgcn_s_setprio(1);                                             \
    _Pragma("unroll")                                                          \
    for (int m = 0; m < 4; ++m)                                                \
      _Pragma("unroll")                                                        \
      for (int n = 0; n < 2; ++n)                                              \
        acc[m][n] = __builtin_amdgcn_mfma_f32_16x16x32_bf16(                   \
            w[n], x[m], acc[m][n], 0, 0, 0);                                   \
    __builtin_amdgcn_s_setprio(0);                                             \
    if ((t) < NT - 2)       asm volatile("s_waitcnt vmcnt(1)" ::: "memory");   \
    else if ((t) == NT - 2) asm volatile("s_waitcnt vmcnt(0)" ::: "memory");   \
    __builtin_amdgcn_s_barrier();                                              \
    /* P2: read w01(t+1); stage B(t+2); Q1 = 4m x n23; read x(t+1); bar */     \
    if ((t) + 1 < NT) {                                                        \
      w[0] = LDF(PBN, 0);                                                      \
      w[1] = LDF(PBN, 1024);                                                   \
    }                                                                          \
    if ((t) + 2 < NT) stageB((CB), (t) + 2);                                   \
    __builtin_amdgcn_s_setprio(1);                                             \
    _Pragma("unroll")                                                          \
    for (int m = 0; m < 4; ++m)                                                \
      _Pragma("unroll")                                                        \
      for (int n = 0; n < 2; ++n)                                              \
        acc[m][n + 2] = __builtin_amdgcn_mfma_f32_16x16x32_bf16(               \
            w[n + 2], x[m], acc[m][n + 2], 0, 0, 0);                           \
    __builtin_amdgcn_s_setprio(0);                                             \
    if ((t) + 1 < NT) {                                                        \
      _Pragma("unroll")                                                        \
      for (int m = 0; m < 4; ++m) x[m] = LDF(PAN, m * 1024);                   \
    }                                                                          \
    __builtin_amdgcn_s_barrier();                                              \
  }

  for (int tt = 0; tt < NT; tt += 2) {
    KTILE(pA0, pB0, pA1, pB1, buf0, tt);
    KTILE(pA1, pB1, pA0, pB0, buf1, tt + 1);
  }
#undef KTILE

  // epilogue: swapped C/D layout -> lane holds 4 consecutive C columns:
  //   Crow = brow + wm*64 + m*16 + r16, Ccol = bcol + wn*64 + n*16 + hi*4 + j
#pragma unroll
  for (int n = 0; n < 4; ++n) {
    const int colb = bcol + wn * 64 + n * 16 + hi * 4;
    const f32x4 bv = *reinterpret_cast<const f32x4*>(&bias[colb]);
#pragma unroll
    for (int m = 0; m < 4; ++m) {
      const size_t row = (size_t)brow + wm * 64 + m * 16 + r16;
      f32x4 v = acc[m][n] + bv;
      *reinterpret_cast<f32x4*>(&C[row * NDIM + colb]) = v;
    }
  }
}

// ---------------------------------------------------------------------------
extern "C" void kernel_launch(void* const* d_in, const int* in_sizes, int n_in,
                              void* d_out, int out_size, void* d_ws, size_t ws_size,
                              hipStream_t stream) {
  const float* x  = (const float*)d_in[0];   // [4,4096,4096]
  const float* W  = (const float*)d_in[1];   // [4096,4096]
  const float* b  = (const float*)d_in[2];   // [4096]
  const float* lA = (const float*)d_in[3];   // [16,4096]
  const float* lB = (const float*)d_in[4];   // [4096,16]
  float* out = (float*)d_out;                // [4,4096,4096] fp32

  unsigned short* xb = (unsigned short*)d_ws;
  unsigned short* Wp = (unsigned short*)((char*)d_ws + (size_t)MDIM * KDIM * 2);

  fused_prep_kernel<<<4096, 256, 0, stream>>>(x, W, lA, lB, xb, Wp);
  gemm128_kernel<<<2048, 512, 0, stream>>>(xb, Wp, b, out);
}

// Round 15
// 590.077 us; speedup vs baseline: 1.1613x; 1.1613x over previous
//
#include <hip/hip_runtime.h>
#include <hip/hip_bf16.h>
#include <cstdint>

// Problem constants (fixed by the reference)
constexpr int  KDIM  = 4096;    // D_IN
constexpr int  NDIM  = 4096;    // D_OUT
constexpr long MDIM  = 16384;   // B*S
constexpr int  RANK_ = 16;
constexpr float SCALE_ = 2.0f;  // alpha/rank

constexpr int BK = 64;
constexpr int NT = KDIM / BK;   // 64 K-tiles

using bf16x8 = __attribute__((ext_vector_type(8))) short;
using f32x4  = __attribute__((ext_vector_type(4))) float;

__device__ __forceinline__ void gload_lds16(const void* g, void* l) {
  __builtin_amdgcn_global_load_lds(
      (const __attribute__((address_space(1))) void*)g,
      (__attribute__((address_space(3))) void*)l, 16, 0, 0);
}

__device__ __forceinline__ unsigned short f2bf(float f) {
  union { float f; unsigned u; } v; v.f = f;
  unsigned r = v.u + 0x7FFFu + ((v.u >> 16) & 1u);
  return (unsigned short)(r >> 16);
}

// immediate-offset LDS fragment read (compiler folds OFF into ds_read offset:)
#define LDF(P, OFF) (*reinterpret_cast<const bf16x8*>((P) + (OFF)))

// ---------------------------------------------------------------------------
// Kernel 1 (fused prologue, R13-proven ~115us ~ HBM floor): block-split
//   blocks [0,512):    Wp = bf16( W + SCALE * lora_B @ lora_A )  [NDIM][KDIM]
//   blocks [512,4096): xb = bf16(x)                              [MDIM][KDIM]
// ---------------------------------------------------------------------------
__global__ __launch_bounds__(256) void fused_prep_kernel(
    const float* __restrict__ x,  const float* __restrict__ W,
    const float* __restrict__ lA, const float* __restrict__ lB,
    unsigned short* __restrict__ xb, unsigned short* __restrict__ Wp) {
  if (blockIdx.x < 512) {
    const long totW = (long)NDIM * KDIM / 8;
    for (long t = blockIdx.x * 256L + threadIdx.x; t < totW; t += 512L * 256) {
      const int o  = (int)(t / (KDIM / 8));
      const int d8 = (int)(t % (KDIM / 8)) * 8;
      const float4* w4 = reinterpret_cast<const float4*>(W + (size_t)o * KDIM + d8);
      float4 w0 = w4[0], w1 = w4[1];
      float acc[8] = {w0.x, w0.y, w0.z, w0.w, w1.x, w1.y, w1.z, w1.w};
#pragma unroll
      for (int r = 0; r < RANK_; ++r) {
        const float br = SCALE_ * lB[o * RANK_ + r];
        const float4* a4 = reinterpret_cast<const float4*>(lA + (size_t)r * KDIM + d8);
        float4 a0 = a4[0], a1 = a4[1];
        acc[0] += br * a0.x; acc[1] += br * a0.y; acc[2] += br * a0.z; acc[3] += br * a0.w;
        acc[4] += br * a1.x; acc[5] += br * a1.y; acc[6] += br * a1.z; acc[7] += br * a1.w;
      }
      uint4 o4;
      o4.x = (unsigned)f2bf(acc[0]) | ((unsigned)f2bf(acc[1]) << 16);
      o4.y = (unsigned)f2bf(acc[2]) | ((unsigned)f2bf(acc[3]) << 16);
      o4.z = (unsigned)f2bf(acc[4]) | ((unsigned)f2bf(acc[5]) << 16);
      o4.w = (unsigned)f2bf(acc[6]) | ((unsigned)f2bf(acc[7]) << 16);
      *reinterpret_cast<uint4*>(Wp + t * 8) = o4;
    }
  } else {
    const long totX = MDIM * KDIM / 8;
    for (long t = (blockIdx.x - 512) * 256L + threadIdx.x; t < totX;
         t += 3584L * 256) {
      const float4* p = reinterpret_cast<const float4*>(x + t * 8);
      float4 a = p[0], b = p[1];
      uint4 o4;
      o4.x = (unsigned)f2bf(a.x) | ((unsigned)f2bf(a.y) << 16);
      o4.y = (unsigned)f2bf(a.z) | ((unsigned)f2bf(a.w) << 16);
      o4.z = (unsigned)f2bf(b.x) | ((unsigned)f2bf(b.y) << 16);
      o4.w = (unsigned)f2bf(b.z) | ((unsigned)f2bf(b.w) << 16);
      *reinterpret_cast<uint4*>(xb + t * 8) = o4;
    }
  }
}

// ---------------------------------------------------------------------------
// Kernel 2: GEMM — byte-identical to R12/R13 (the measured best: 466us,
//   MfmaUtil 54.5, 0 conflicts). Structure summary:
//   256x256 tile, 16x16x32 MFMA, 4 phases/K-tile, phase-ahead register loads,
//   early-issue staging (A(t+1)@P1, B(t+2)@P3), counted vmcnt(4)@P4,
//   st_16x32-family LDS swizzle (verified 0-conflict), imm-offset ds_reads,
//   XCD-bijective block swizzle, swapped-operand dwordx4 epilogue.
// ---------------------------------------------------------------------------
__global__ __launch_bounds__(512, 2) void gemm256_kernel(
    const unsigned short* __restrict__ A,   // [MDIM][KDIM] bf16 bits (x)
    const unsigned short* __restrict__ Bm,  // [NDIM][KDIM] bf16 bits (W')
    const float* __restrict__ bias,
    float* __restrict__ C) {
  __shared__ __align__(16) unsigned char lds[131072];

  const int tid  = threadIdx.x;
  const int wave = tid >> 6, lane = tid & 63;
  const int wm = wave >> 2, wn = wave & 3;       // 2 x 4 wave grid
  const int r16 = lane & 15, hi = lane >> 4;
  const int swz5 = ((r16 >> 3) & 1) << 5;        // verified-0-conflict swizzle
  const int lrB = (wn & 1) * 64;

  // XCD-aware bijective blockIdx swizzle, R4 orientation (verified lower fetch)
  const int orig = blockIdx.x;
  const int bid  = (orig & 7) * 128 + (orig >> 3);
  const int bcol = (bid & 15) * 256;             // N-tile
  const int brow = (bid >> 4) * 256;             // M-tile

  // staging geometry (verified R2): linear LDS dest + inverse-swizzled source
  const int st_row = wave * 16 + (lane >> 2);                     // 0..127
  const int st_col = ((lane & 3) * 8) ^ (((lane >> 5) & 1) << 4); // elem [0,32)
  const unsigned short* Asrc = A  + (size_t)(brow + st_row) * KDIM + st_col;
  const unsigned short* Bsrc = Bm + (size_t)(bcol + st_row) * KDIM + st_col;

  // stage half-tile s (0=B0,1=B1,2=A0,3=A1) of K-tile tau into buffer `base`
  auto stageHalf = [&](unsigned char* base, int s, int tau) {
    const unsigned short* g = (s >= 2 ? Asrc + (size_t)(s - 2) * 128 * KDIM
                                      : Bsrc + (size_t)s * 128 * KDIM) + tau * BK;
    unsigned char* d = base + (wave << 10) + s * 16384;
    gload_lds16(g,      d);            // kk0
    gload_lds16(g + 32, d + 8192);     // kk1
  };

  // per-lane ds-read base pointers; every fragment read = base + const offset:
  //   A frag (row m*16+r16, kk):      pA + m*1024 + kk*8192      (m 0..7)
  //   B frag (row lrB+n*16+r16, kk):  pB + n*1024 + kk*8192      (n 0..3)
  const int laneoff = r16 * 64 + ((hi * 16) ^ swz5);
  const unsigned char* pA0 = lds + (2 + wm) * 16384 + laneoff;
  const unsigned char* pB0 = lds + (wn >> 1) * 16384 + lrB * 64 + laneoff;
  const unsigned char* pA1 = pA0 + 65536;
  const unsigned char* pB1 = pB0 + 65536;

  f32x4 acc[8][4];
#pragma unroll
  for (int m = 0; m < 8; ++m)
#pragma unroll
    for (int n = 0; n < 4; ++n) acc[m][n] = (f32x4){0.f, 0.f, 0.f, 0.f};

  unsigned char* const buf0 = lds;
  unsigned char* const buf1 = lds + 65536;

  // prologue: tile0 full (buf0) + tile1 B0,B1 (buf1); vmcnt(4) retires tile0
  // (8 oldest loads), leaves B(1) in flight = steady-state invariant.
  stageHalf(buf0, 0, 0); stageHalf(buf0, 1, 0);
  stageHalf(buf0, 2, 0); stageHalf(buf0, 3, 0);
  stageHalf(buf1, 0, 1); stageHalf(buf1, 1, 1);
  asm volatile("s_waitcnt vmcnt(4)" ::: "memory");
  __builtin_amdgcn_s_barrier();

  bf16x8 xlo[4][2], xhi[4][2], wlo[2][2], whi[2][2];
  // boundary pre-read for tile 0: xlo (both kk) from buf0
#pragma unroll
  for (int m = 0; m < 4; ++m) {
    xlo[m][0] = LDF(pA0, m * 1024);
    xlo[m][1] = LDF(pA0, m * 1024 + 8192);
  }

  // One K-tile. CB/NB = cur/next staging buffer; PA/PB = cur read bases;
  // PAN = next A read base; t = tile index.
#define KTILE(CB, NB, PA, PB, PAN, t)                                          \
  {                                                                            \
    /* P1: read wlo+whi(t) (8); stage A0+A1(t+1); Q0 (xlo from prev P4) */     \
    _Pragma("unroll")                                                          \
    for (int n = 0; n < 2; ++n) {                                              \
      wlo[n][0] = LDF(PB, n * 1024);                                           \
      wlo[n][1] = LDF(PB, n * 1024 + 8192);                                    \
    }                                                                          \
    _Pragma("unroll")                                                          \
    for (int n = 0; n < 2; ++n) {                                              \
      whi[n][0] = LDF(PB, (n + 2) * 1024);                                     \
      whi[n][1] = LDF(PB, (n + 2) * 1024 + 8192);                              \
    }                                                                          \
    if ((t) + 1 < NT) { stageHalf((NB), 2, (t) + 1);                           \
                        stageHalf((NB), 3, (t) + 1); }                         \
    __builtin_amdgcn_s_setprio(1);                                             \
    _Pragma("unroll")                                                          \
    for (int kk = 0; kk < 2; ++kk)                                             \
      _Pragma("unroll")                                                        \
      for (int m = 0; m < 4; ++m)                                              \
        _Pragma("unroll")                                                      \
        for (int n = 0; n < 2; ++n)                                            \
          acc[m][n] = __builtin_amdgcn_mfma_f32_16x16x32_bf16(                 \
              wlo[n][kk], xlo[m][kk], acc[m][n], 0, 0, 0);                     \
    __builtin_amdgcn_s_setprio(0);                                             \
    __builtin_amdgcn_s_barrier();                                              \
    /* P2: read xhi(t) (8); Q1 (whi read P1); bar */                           \
    _Pragma("unroll")                                                          \
    for (int m = 0; m < 4; ++m) {                                              \
      xhi[m][0] = LDF(PA, (m + 4) * 1024);                                     \
      xhi[m][1] = LDF(PA, (m + 4) * 1024 + 8192);                              \
    }                                                                          \
    __builtin_amdgcn_s_setprio(1);                                             \
    _Pragma("unroll")                                                          \
    for (int kk = 0; kk < 2; ++kk)                                             \
      _Pragma("unroll")                                                        \
      for (int m = 0; m < 4; ++m)                                              \
        _Pragma("unroll")                                                      \
        for (int n = 0; n < 2; ++n)                                            \
          acc[m][n + 2] = __builtin_amdgcn_mfma_f32_16x16x32_bf16(             \
              whi[n][kk], xlo[m][kk], acc[m][n + 2], 0, 0, 0);                 \
    __builtin_amdgcn_s_setprio(0);                                             \
    __builtin_amdgcn_s_barrier();                                              \
    /* P3: no reads; stage B0+B1(t+2) into CB; Q2 (xhi read P2); bar */        \
    if ((t) + 2 < NT) { stageHalf((CB), 0, (t) + 2);                           \
                        stageHalf((CB), 1, (t) + 2); }                         \
    __builtin_amdgcn_s_setprio(1);                                             \
    _Pragma("unroll")                                                          \
    for (int kk = 0; kk < 2; ++kk)                                             \
      _Pragma("unroll")                                                        \
      for (int m = 0; m < 4; ++m)                                              \
        _Pragma("unroll")                                                      \
        for (int n = 0; n < 2; ++n)                                            \
          acc[m + 4][n + 2] = __builtin_amdgcn_mfma_f32_16x16x32_bf16(         \
              whi[n][kk], xhi[m][kk], acc[m + 4][n + 2], 0, 0, 0);             \
    __builtin_amdgcn_s_setprio(0);                                             \
    __builtin_amdgcn_s_barrier();                                              \
    /* P4: vmcnt(4) -> all of t+1 resident (A ages 3 phases), B(t+2) in        \
       flight; bar; boundary read xlo(t+1) (8) overlaps Q3 */                  \
    if ((t) < NT - 2)       asm volatile("s_waitcnt vmcnt(4)" ::: "memory");   \
    else if ((t) == NT - 2) asm volatile("s_waitcnt vmcnt(0)" ::: "memory");   \
    __builtin_amdgcn_s_barrier();                                              \
    if ((t) + 1 < NT) {                                                        \
      _Pragma("unroll")                                                        \
      for (int m = 0; m < 4; ++m) {                                            \
        xlo[m][0] = LDF(PAN, m * 1024);                                        \
        xlo[m][1] = LDF(PAN, m * 1024 + 8192);                                 \
      }                                                                        \
    }                                                                          \
    __builtin_amdgcn_s_setprio(1);                                             \
    _Pragma("unroll")                                                          \
    for (int kk = 0; kk < 2; ++kk)                                             \
      _Pragma("unroll")                                                        \
      for (int m = 0; m < 4; ++m)                                              \
        _Pragma("unroll")                                                      \
        for (int n = 0; n < 2; ++n)                                            \
          acc[m + 4][n] = __builtin_amdgcn_mfma_f32_16x16x32_bf16(             \
              wlo[n][kk], xhi[m][kk], acc[m + 4][n], 0, 0, 0);                 \
    __builtin_amdgcn_s_setprio(0);                                             \
  }

  for (int tt = 0; tt < NT; tt += 2) {
    KTILE(buf0, buf1, pA0, pB0, pA1, tt);
    KTILE(buf1, buf0, pA1, pB1, pA0, tt + 1);
  }
#undef KTILE

  // epilogue (verified R3/R4): swapped C/D layout -> lane holds 4 consecutive
  // C columns: Crow = brow + wm*128 + m*16 + (lane&15),
  //            Ccol = bcol + wn*64 + n*16 + hi*4 + j  -> dwordx4 stores
#pragma unroll
  for (int n = 0; n < 4; ++n) {
    const int colb = bcol + wn * 64 + n * 16 + hi * 4;
    const f32x4 bv = *reinterpret_cast<const f32x4*>(&bias[colb]);
#pragma unroll
    for (int m = 0; m < 8; ++m) {
      const size_t row = (size_t)brow + wm * 128 + m * 16 + r16;
      f32x4 v = acc[m][n] + bv;
      *reinterpret_cast<f32x4*>(&C[row * NDIM + colb]) = v;
    }
  }
}

// ---------------------------------------------------------------------------
extern "C" void kernel_launch(void* const* d_in, const int* in_sizes, int n_in,
                              void* d_out, int out_size, void* d_ws, size_t ws_size,
                              hipStream_t stream) {
  const float* x  = (const float*)d_in[0];   // [4,4096,4096]
  const float* W  = (const float*)d_in[1];   // [4096,4096]
  const float* b  = (const float*)d_in[2];   // [4096]
  const float* lA = (const float*)d_in[3];   // [16,4096]
  const float* lB = (const float*)d_in[4];   // [4096,16]
  float* out = (float*)d_out;                // [4,4096,4096] fp32

  unsigned short* xb = (unsigned short*)d_ws;
  unsigned short* Wp = (unsigned short*)((char*)d_ws + (size_t)MDIM * KDIM * 2);

  fused_prep_kernel<<<4096, 256, 0, stream>>>(x, W, lA, lB, xb, Wp);
  gemm256_kernel<<<1024, 512, 0, stream>>>(xb, Wp, b, out);
}

// Round 16
// 579.942 us; speedup vs baseline: 1.1816x; 1.0175x over previous
//
#include <hip/hip_runtime.h>
#include <hip/hip_bf16.h>
#include <cstdint>

// Problem constants (fixed by the reference)
constexpr int  KDIM  = 4096;    // D_IN
constexpr int  NDIM  = 4096;    // D_OUT
constexpr long MDIM  = 16384;   // B*S
constexpr int  RANK_ = 16;
constexpr float SCALE_ = 2.0f;  // alpha/rank

constexpr int BK = 64;
constexpr int NT = KDIM / BK;   // 64 K-tiles

using bf16x8 = __attribute__((ext_vector_type(8))) short;
using f32x4  = __attribute__((ext_vector_type(4))) float;

__device__ __forceinline__ void gload_lds16(const void* g, void* l) {
  __builtin_amdgcn_global_load_lds(
      (const __attribute__((address_space(1))) void*)g,
      (__attribute__((address_space(3))) void*)l, 16, 0, 0);
}

__device__ __forceinline__ unsigned short f2bf(float f) {
  union { float f; unsigned u; } v; v.f = f;
  unsigned r = v.u + 0x7FFFu + ((v.u >> 16) & 1u);
  return (unsigned short)(r >> 16);
}

// immediate-offset LDS fragment read (compiler folds OFF into ds_read offset:)
#define LDF(P, OFF) (*reinterpret_cast<const bf16x8*>((P) + (OFF)))

// ---------------------------------------------------------------------------
// Kernel 1 (fused prologue): block-split
//   blocks [0,512):    Wp = bf16( W + SCALE * lora_B @ lora_A )  [NDIM][KDIM]
//   blocks [512,4096): xb = bf16(x)                              [MDIM][KDIM]
// NT loads on the read-once x/W streams so they don't evict xb/Wp from L3
// (the GEMM reads xb 16x / Wp 64x right after).
// ---------------------------------------------------------------------------
__global__ __launch_bounds__(256) void fused_prep_kernel(
    const float* __restrict__ x,  const float* __restrict__ W,
    const float* __restrict__ lA, const float* __restrict__ lB,
    unsigned short* __restrict__ xb, unsigned short* __restrict__ Wp) {
  if (blockIdx.x < 512) {
    const long totW = (long)NDIM * KDIM / 8;
    for (long t = blockIdx.x * 256L + threadIdx.x; t < totW; t += 512L * 256) {
      const int o  = (int)(t / (KDIM / 8));
      const int d8 = (int)(t % (KDIM / 8)) * 8;
      const f32x4* w4 = reinterpret_cast<const f32x4*>(W + (size_t)o * KDIM + d8);
      f32x4 w0 = __builtin_nontemporal_load(w4);
      f32x4 w1 = __builtin_nontemporal_load(w4 + 1);
      float acc[8] = {w0[0], w0[1], w0[2], w0[3], w1[0], w1[1], w1[2], w1[3]};
#pragma unroll
      for (int r = 0; r < RANK_; ++r) {
        const float br = SCALE_ * lB[o * RANK_ + r];
        const float4* a4 = reinterpret_cast<const float4*>(lA + (size_t)r * KDIM + d8);
        float4 a0 = a4[0], a1 = a4[1];
        acc[0] += br * a0.x; acc[1] += br * a0.y; acc[2] += br * a0.z; acc[3] += br * a0.w;
        acc[4] += br * a1.x; acc[5] += br * a1.y; acc[6] += br * a1.z; acc[7] += br * a1.w;
      }
      uint4 o4;
      o4.x = (unsigned)f2bf(acc[0]) | ((unsigned)f2bf(acc[1]) << 16);
      o4.y = (unsigned)f2bf(acc[2]) | ((unsigned)f2bf(acc[3]) << 16);
      o4.z = (unsigned)f2bf(acc[4]) | ((unsigned)f2bf(acc[5]) << 16);
      o4.w = (unsigned)f2bf(acc[6]) | ((unsigned)f2bf(acc[7]) << 16);
      *reinterpret_cast<uint4*>(Wp + t * 8) = o4;
    }
  } else {
    const long totX = MDIM * KDIM / 8;
    for (long t = (blockIdx.x - 512) * 256L + threadIdx.x; t < totX;
         t += 3584L * 256) {
      const f32x4* p = reinterpret_cast<const f32x4*>(x + t * 8);
      f32x4 a = __builtin_nontemporal_load(p);
      f32x4 b = __builtin_nontemporal_load(p + 1);
      uint4 o4;
      o4.x = (unsigned)f2bf(a[0]) | ((unsigned)f2bf(a[1]) << 16);
      o4.y = (unsigned)f2bf(a[2]) | ((unsigned)f2bf(a[3]) << 16);
      o4.z = (unsigned)f2bf(b[0]) | ((unsigned)f2bf(b[1]) << 16);
      o4.w = (unsigned)f2bf(b[2]) | ((unsigned)f2bf(b[3]) << 16);
      *reinterpret_cast<uint4*>(xb + t * 8) = o4;
    }
  }
}

// ---------------------------------------------------------------------------
// Kernel 2: GEMM — inner loop byte-identical to R13/R15 (measured best:
//   466-476us, MfmaUtil 54.5, 0 conflicts). Single delta: NONTEMPORAL C
//   stores in the epilogue so the 268MB write-once stream doesn't thrash
//   the 256MB L3 that should be holding x(134MB)+W'(32MB) for reuse.
//   Structure: 256x256 tile, 16x16x32 MFMA, 4 phases/K-tile, phase-ahead
//   register loads, early-issue staging (A(t+1)@P1, B(t+2)@P3), counted
//   vmcnt(4)@P4, verified-0-conflict swizzle, imm-offset ds_reads,
//   XCD-bijective block swizzle, swapped-operand dwordx4 epilogue.
// ---------------------------------------------------------------------------
__global__ __launch_bounds__(512, 2) void gemm256_kernel(
    const unsigned short* __restrict__ A,   // [MDIM][KDIM] bf16 bits (x)
    const unsigned short* __restrict__ Bm,  // [NDIM][KDIM] bf16 bits (W')
    const float* __restrict__ bias,
    float* __restrict__ C) {
  __shared__ __align__(16) unsigned char lds[131072];

  const int tid  = threadIdx.x;
  const int wave = tid >> 6, lane = tid & 63;
  const int wm = wave >> 2, wn = wave & 3;       // 2 x 4 wave grid
  const int r16 = lane & 15, hi = lane >> 4;
  const int swz5 = ((r16 >> 3) & 1) << 5;        // verified-0-conflict swizzle
  const int lrB = (wn & 1) * 64;

  // XCD-aware bijective blockIdx swizzle, R4 orientation (verified lower fetch)
  const int orig = blockIdx.x;
  const int bid  = (orig & 7) * 128 + (orig >> 3);
  const int bcol = (bid & 15) * 256;             // N-tile
  const int brow = (bid >> 4) * 256;             // M-tile

  // staging geometry (verified R2): linear LDS dest + inverse-swizzled source
  const int st_row = wave * 16 + (lane >> 2);                     // 0..127
  const int st_col = ((lane & 3) * 8) ^ (((lane >> 5) & 1) << 4); // elem [0,32)
  const unsigned short* Asrc = A  + (size_t)(brow + st_row) * KDIM + st_col;
  const unsigned short* Bsrc = Bm + (size_t)(bcol + st_row) * KDIM + st_col;

  // stage half-tile s (0=B0,1=B1,2=A0,3=A1) of K-tile tau into buffer `base`
  auto stageHalf = [&](unsigned char* base, int s, int tau) {
    const unsigned short* g = (s >= 2 ? Asrc + (size_t)(s - 2) * 128 * KDIM
                                      : Bsrc + (size_t)s * 128 * KDIM) + tau * BK;
    unsigned char* d = base + (wave << 10) + s * 16384;
    gload_lds16(g,      d);            // kk0
    gload_lds16(g + 32, d + 8192);     // kk1
  };

  // per-lane ds-read base pointers; every fragment read = base + const offset:
  //   A frag (row m*16+r16, kk):      pA + m*1024 + kk*8192      (m 0..7)
  //   B frag (row lrB+n*16+r16, kk):  pB + n*1024 + kk*8192      (n 0..3)
  const int laneoff = r16 * 64 + ((hi * 16) ^ swz5);
  const unsigned char* pA0 = lds + (2 + wm) * 16384 + laneoff;
  const unsigned char* pB0 = lds + (wn >> 1) * 16384 + lrB * 64 + laneoff;
  const unsigned char* pA1 = pA0 + 65536;
  const unsigned char* pB1 = pB0 + 65536;

  f32x4 acc[8][4];
#pragma unroll
  for (int m = 0; m < 8; ++m)
#pragma unroll
    for (int n = 0; n < 4; ++n) acc[m][n] = (f32x4){0.f, 0.f, 0.f, 0.f};

  unsigned char* const buf0 = lds;
  unsigned char* const buf1 = lds + 65536;

  // prologue: tile0 full (buf0) + tile1 B0,B1 (buf1); vmcnt(4) retires tile0
  // (8 oldest loads), leaves B(1) in flight = steady-state invariant.
  stageHalf(buf0, 0, 0); stageHalf(buf0, 1, 0);
  stageHalf(buf0, 2, 0); stageHalf(buf0, 3, 0);
  stageHalf(buf1, 0, 1); stageHalf(buf1, 1, 1);
  asm volatile("s_waitcnt vmcnt(4)" ::: "memory");
  __builtin_amdgcn_s_barrier();

  bf16x8 xlo[4][2], xhi[4][2], wlo[2][2], whi[2][2];
  // boundary pre-read for tile 0: xlo (both kk) from buf0
#pragma unroll
  for (int m = 0; m < 4; ++m) {
    xlo[m][0] = LDF(pA0, m * 1024);
    xlo[m][1] = LDF(pA0, m * 1024 + 8192);
  }

  // One K-tile. CB/NB = cur/next staging buffer; PA/PB = cur read bases;
  // PAN = next A read base; t = tile index.
#define KTILE(CB, NB, PA, PB, PAN, t)                                          \
  {                                                                            \
    /* P1: read wlo+whi(t) (8); stage A0+A1(t+1); Q0 (xlo from prev P4) */     \
    _Pragma("unroll")                                                          \
    for (int n = 0; n < 2; ++n) {                                              \
      wlo[n][0] = LDF(PB, n * 1024);                                           \
      wlo[n][1] = LDF(PB, n * 1024 + 8192);                                    \
    }                                                                          \
    _Pragma("unroll")                                                          \
    for (int n = 0; n < 2; ++n) {                                              \
      whi[n][0] = LDF(PB, (n + 2) * 1024);                                     \
      whi[n][1] = LDF(PB, (n + 2) * 1024 + 8192);                              \
    }                                                                          \
    if ((t) + 1 < NT) { stageHalf((NB), 2, (t) + 1);                           \
                        stageHalf((NB), 3, (t) + 1); }                         \
    __builtin_amdgcn_s_setprio(1);                                             \
    _Pragma("unroll")                                                          \
    for (int kk = 0; kk < 2; ++kk)                                             \
      _Pragma("unroll")                                                        \
      for (int m = 0; m < 4; ++m)                                              \
        _Pragma("unroll")                                                      \
        for (int n = 0; n < 2; ++n)                                            \
          acc[m][n] = __builtin_amdgcn_mfma_f32_16x16x32_bf16(                 \
              wlo[n][kk], xlo[m][kk], acc[m][n], 0, 0, 0);                     \
    __builtin_amdgcn_s_setprio(0);                                             \
    __builtin_amdgcn_s_barrier();                                              \
    /* P2: read xhi(t) (8); Q1 (whi read P1); bar */                           \
    _Pragma("unroll")                                                          \
    for (int m = 0; m < 4; ++m) {                                              \
      xhi[m][0] = LDF(PA, (m + 4) * 1024);                                     \
      xhi[m][1] = LDF(PA, (m + 4) * 1024 + 8192);                              \
    }                                                                          \
    __builtin_amdgcn_s_setprio(1);                                             \
    _Pragma("unroll")                                                          \
    for (int kk = 0; kk < 2; ++kk)                                             \
      _Pragma("unroll")                                                        \
      for (int m = 0; m < 4; ++m)                                              \
        _Pragma("unroll")                                                      \
        for (int n = 0; n < 2; ++n)                                            \
          acc[m][n + 2] = __builtin_amdgcn_mfma_f32_16x16x32_bf16(             \
              whi[n][kk], xlo[m][kk], acc[m][n + 2], 0, 0, 0);                 \
    __builtin_amdgcn_s_setprio(0);                                             \
    __builtin_amdgcn_s_barrier();                                              \
    /* P3: no reads; stage B0+B1(t+2) into CB; Q2 (xhi read P2); bar */        \
    if ((t) + 2 < NT) { stageHalf((CB), 0, (t) + 2);                           \
                        stageHalf((CB), 1, (t) + 2); }                         \
    __builtin_amdgcn_s_setprio(1);                                             \
    _Pragma("unroll")                                                          \
    for (int kk = 0; kk < 2; ++kk)                                             \
      _Pragma("unroll")                                                        \
      for (int m = 0; m < 4; ++m)                                              \
        _Pragma("unroll")                                                      \
        for (int n = 0; n < 2; ++n)                                            \
          acc[m + 4][n + 2] = __builtin_amdgcn_mfma_f32_16x16x32_bf16(         \
              whi[n][kk], xhi[m][kk], acc[m + 4][n + 2], 0, 0, 0);             \
    __builtin_amdgcn_s_setprio(0);                                             \
    __builtin_amdgcn_s_barrier();                                              \
    /* P4: vmcnt(4) -> all of t+1 resident (A ages 3 phases), B(t+2) in        \
       flight; bar; boundary read xlo(t+1) (8) overlaps Q3 */                  \
    if ((t) < NT - 2)       asm volatile("s_waitcnt vmcnt(4)" ::: "memory");   \
    else if ((t) == NT - 2) asm volatile("s_waitcnt vmcnt(0)" ::: "memory");   \
    __builtin_amdgcn_s_barrier();                                              \
    if ((t) + 1 < NT) {                                                        \
      _Pragma("unroll")                                                        \
      for (int m = 0; m < 4; ++m) {                                            \
        xlo[m][0] = LDF(PAN, m * 1024);                                        \
        xlo[m][1] = LDF(PAN, m * 1024 + 8192);                                 \
      }                                                                        \
    }                                                                          \
    __builtin_amdgcn_s_setprio(1);                                             \
    _Pragma("unroll")                                                          \
    for (int kk = 0; kk < 2; ++kk)                                             \
      _Pragma("unroll")                                                        \
      for (int m = 0; m < 4; ++m)                                              \
        _Pragma("unroll")                                                      \
        for (int n = 0; n < 2; ++n)                                            \
          acc[m + 4][n] = __builtin_amdgcn_mfma_f32_16x16x32_bf16(             \
              wlo[n][kk], xhi[m][kk], acc[m + 4][n], 0, 0, 0);                 \
    __builtin_amdgcn_s_setprio(0);                                             \
  }

  for (int tt = 0; tt < NT; tt += 2) {
    KTILE(buf0, buf1, pA0, pB0, pA1, tt);
    KTILE(buf1, buf0, pA1, pB1, pA0, tt + 1);
  }
#undef KTILE

  // epilogue: swapped C/D layout -> lane holds 4 consecutive C columns:
  //   Crow = brow + wm*128 + m*16 + (lane&15),
  //   Ccol = bcol + wn*64 + n*16 + hi*4 + j  -> NONTEMPORAL dwordx4 stores
  //   (C is write-once; keep it out of L3 so x/W' panels stay resident)
#pragma unroll
  for (int n = 0; n < 4; ++n) {
    const int colb = bcol + wn * 64 + n * 16 + hi * 4;
    const f32x4 bv = *reinterpret_cast<const f32x4*>(&bias[colb]);
#pragma unroll
    for (int m = 0; m < 8; ++m) {
      const size_t row = (size_t)brow + wm * 128 + m * 16 + r16;
      f32x4 v = acc[m][n] + bv;
      __builtin_nontemporal_store(v, reinterpret_cast<f32x4*>(&C[row * NDIM + colb]));
    }
  }
}

// ---------------------------------------------------------------------------
extern "C" void kernel_launch(void* const* d_in, const int* in_sizes, int n_in,
                              void* d_out, int out_size, void* d_ws, size_t ws_size,
                              hipStream_t stream) {
  const float* x  = (const float*)d_in[0];   // [4,4096,4096]
  const float* W  = (const float*)d_in[1];   // [4096,4096]
  const float* b  = (const float*)d_in[2];   // [4096]
  const float* lA = (const float*)d_in[3];   // [16,4096]
  const float* lB = (const float*)d_in[4];   // [4096,16]
  float* out = (float*)d_out;                // [4,4096,4096] fp32

  unsigned short* xb = (unsigned short*)d_ws;
  unsigned short* Wp = (unsigned short*)((char*)d_ws + (size_t)MDIM * KDIM * 2);

  fused_prep_kernel<<<4096, 256, 0, stream>>>(x, W, lA, lB, xb, Wp);
  gemm256_kernel<<<1024, 512, 0, stream>>>(xb, Wp, b, out);
}

// Round 17
// 575.638 us; speedup vs baseline: 1.1904x; 1.0075x over previous
//
#include <hip/hip_runtime.h>
#include <hip/hip_bf16.h>
#include <cstdint>

// Problem constants (fixed by the reference)
constexpr int  KDIM  = 4096;    // D_IN
constexpr int  NDIM  = 4096;    // D_OUT
constexpr long MDIM  = 16384;   // B*S
constexpr int  RANK_ = 16;
constexpr float SCALE_ = 2.0f;  // alpha/rank

constexpr int BK = 64;
constexpr int NT = KDIM / BK;   // 64 K-tiles

using bf16x8 = __attribute__((ext_vector_type(8))) short;
using f32x4  = __attribute__((ext_vector_type(4))) float;

__device__ __forceinline__ void gload_lds16(const void* g, void* l) {
  __builtin_amdgcn_global_load_lds(
      (const __attribute__((address_space(1))) void*)g,
      (__attribute__((address_space(3))) void*)l, 16, 0, 0);
}

__device__ __forceinline__ unsigned short f2bf(float f) {
  union { float f; unsigned u; } v; v.f = f;
  unsigned r = v.u + 0x7FFFu + ((v.u >> 16) & 1u);
  return (unsigned short)(r >> 16);
}

// immediate-offset LDS fragment read (compiler folds OFF into ds_read offset:)
#define LDF(P, OFF) (*reinterpret_cast<const bf16x8*>((P) + (OFF)))

// ---------------------------------------------------------------------------
// Kernel 1 (fused prologue, R16-proven): block-split
//   blocks [0,512):    Wp = bf16( W + SCALE * lora_B @ lora_A )  [NDIM][KDIM]
//   blocks [512,4096): xb = bf16(x)                              [MDIM][KDIM]
// NT loads on the read-once x/W streams.
// ---------------------------------------------------------------------------
__global__ __launch_bounds__(256) void fused_prep_kernel(
    const float* __restrict__ x,  const float* __restrict__ W,
    const float* __restrict__ lA, const float* __restrict__ lB,
    unsigned short* __restrict__ xb, unsigned short* __restrict__ Wp) {
  if (blockIdx.x < 512) {
    const long totW = (long)NDIM * KDIM / 8;
    for (long t = blockIdx.x * 256L + threadIdx.x; t < totW; t += 512L * 256) {
      const int o  = (int)(t / (KDIM / 8));
      const int d8 = (int)(t % (KDIM / 8)) * 8;
      const f32x4* w4 = reinterpret_cast<const f32x4*>(W + (size_t)o * KDIM + d8);
      f32x4 w0 = __builtin_nontemporal_load(w4);
      f32x4 w1 = __builtin_nontemporal_load(w4 + 1);
      float acc[8] = {w0[0], w0[1], w0[2], w0[3], w1[0], w1[1], w1[2], w1[3]};
#pragma unroll
      for (int r = 0; r < RANK_; ++r) {
        const float br = SCALE_ * lB[o * RANK_ + r];
        const float4* a4 = reinterpret_cast<const float4*>(lA + (size_t)r * KDIM + d8);
        float4 a0 = a4[0], a1 = a4[1];
        acc[0] += br * a0.x; acc[1] += br * a0.y; acc[2] += br * a0.z; acc[3] += br * a0.w;
        acc[4] += br * a1.x; acc[5] += br * a1.y; acc[6] += br * a1.z; acc[7] += br * a1.w;
      }
      uint4 o4;
      o4.x = (unsigned)f2bf(acc[0]) | ((unsigned)f2bf(acc[1]) << 16);
      o4.y = (unsigned)f2bf(acc[2]) | ((unsigned)f2bf(acc[3]) << 16);
      o4.z = (unsigned)f2bf(acc[4]) | ((unsigned)f2bf(acc[5]) << 16);
      o4.w = (unsigned)f2bf(acc[6]) | ((unsigned)f2bf(acc[7]) << 16);
      *reinterpret_cast<uint4*>(Wp + t * 8) = o4;
    }
  } else {
    const long totX = MDIM * KDIM / 8;
    for (long t = (blockIdx.x - 512) * 256L + threadIdx.x; t < totX;
         t += 3584L * 256) {
      const f32x4* p = reinterpret_cast<const f32x4*>(x + t * 8);
      f32x4 a = __builtin_nontemporal_load(p);
      f32x4 b = __builtin_nontemporal_load(p + 1);
      uint4 o4;
      o4.x = (unsigned)f2bf(a[0]) | ((unsigned)f2bf(a[1]) << 16);
      o4.y = (unsigned)f2bf(a[2]) | ((unsigned)f2bf(a[3]) << 16);
      o4.z = (unsigned)f2bf(b[0]) | ((unsigned)f2bf(b[1]) << 16);
      o4.w = (unsigned)f2bf(b[2]) | ((unsigned)f2bf(b[3]) << 16);
      *reinterpret_cast<uint4*>(xb + t * 8) = o4;
    }
  }
}

// ---------------------------------------------------------------------------
// Kernel 2: GEMM = R16 (457us, MfmaUtil 57.5, 0 conflicts, nt C-stores)
//   + ZERO same-phase read->MFMA dependency:
//     P1: read whi(t) (4);  stage A0+A1(t+1); Q0 (wlo,xlo from P4(t-1)); bar
//     P2: read xhi(t) (8);  Q1 (whi read P1); bar
//     P3: stage B0+B1(t+2); Q2 (xhi read P2); bar
//     P4: vmcnt(4); bar; Q3 FIRST (consumes wlo(t),xhi(t)); THEN read
//         wlo(t+1)(4)+xlo(t+1)(8) into the same regs (WAR via in-order
//         issue, no double-buffer -> no R9 spill). Reads drain across the
//         phase boundary into P1 with the LDS pipe idle.
//   All other structure identical to R16.
// ---------------------------------------------------------------------------
__global__ __launch_bounds__(512, 2) void gemm256_kernel(
    const unsigned short* __restrict__ A,   // [MDIM][KDIM] bf16 bits (x)
    const unsigned short* __restrict__ Bm,  // [NDIM][KDIM] bf16 bits (W')
    const float* __restrict__ bias,
    float* __restrict__ C) {
  __shared__ __align__(16) unsigned char lds[131072];

  const int tid  = threadIdx.x;
  const int wave = tid >> 6, lane = tid & 63;
  const int wm = wave >> 2, wn = wave & 3;       // 2 x 4 wave grid
  const int r16 = lane & 15, hi = lane >> 4;
  const int swz5 = ((r16 >> 3) & 1) << 5;        // verified-0-conflict swizzle
  const int lrB = (wn & 1) * 64;

  // XCD-aware bijective blockIdx swizzle, R4 orientation (verified lower fetch)
  const int orig = blockIdx.x;
  const int bid  = (orig & 7) * 128 + (orig >> 3);
  const int bcol = (bid & 15) * 256;             // N-tile
  const int brow = (bid >> 4) * 256;             // M-tile

  // staging geometry (verified R2): linear LDS dest + inverse-swizzled source
  const int st_row = wave * 16 + (lane >> 2);                     // 0..127
  const int st_col = ((lane & 3) * 8) ^ (((lane >> 5) & 1) << 4); // elem [0,32)
  const unsigned short* Asrc = A  + (size_t)(brow + st_row) * KDIM + st_col;
  const unsigned short* Bsrc = Bm + (size_t)(bcol + st_row) * KDIM + st_col;

  // stage half-tile s (0=B0,1=B1,2=A0,3=A1) of K-tile tau into buffer `base`
  auto stageHalf = [&](unsigned char* base, int s, int tau) {
    const unsigned short* g = (s >= 2 ? Asrc + (size_t)(s - 2) * 128 * KDIM
                                      : Bsrc + (size_t)s * 128 * KDIM) + tau * BK;
    unsigned char* d = base + (wave << 10) + s * 16384;
    gload_lds16(g,      d);            // kk0
    gload_lds16(g + 32, d + 8192);     // kk1
  };

  // per-lane ds-read base pointers; every fragment read = base + const offset:
  //   A frag (row m*16+r16, kk):      pA + m*1024 + kk*8192      (m 0..7)
  //   B frag (row lrB+n*16+r16, kk):  pB + n*1024 + kk*8192      (n 0..3)
  const int laneoff = r16 * 64 + ((hi * 16) ^ swz5);
  const unsigned char* pA0 = lds + (2 + wm) * 16384 + laneoff;
  const unsigned char* pB0 = lds + (wn >> 1) * 16384 + lrB * 64 + laneoff;
  const unsigned char* pA1 = pA0 + 65536;
  const unsigned char* pB1 = pB0 + 65536;

  f32x4 acc[8][4];
#pragma unroll
  for (int m = 0; m < 8; ++m)
#pragma unroll
    for (int n = 0; n < 4; ++n) acc[m][n] = (f32x4){0.f, 0.f, 0.f, 0.f};

  unsigned char* const buf0 = lds;
  unsigned char* const buf1 = lds + 65536;

  // prologue: tile0 full (buf0) + tile1 B0,B1 (buf1); vmcnt(4) retires tile0
  // (8 oldest loads), leaves B(1) in flight = steady-state invariant.
  stageHalf(buf0, 0, 0); stageHalf(buf0, 1, 0);
  stageHalf(buf0, 2, 0); stageHalf(buf0, 3, 0);
  stageHalf(buf1, 0, 1); stageHalf(buf1, 1, 1);
  asm volatile("s_waitcnt vmcnt(4)" ::: "memory");
  __builtin_amdgcn_s_barrier();

  bf16x8 xlo[4][2], xhi[4][2], wlo[2][2], whi[2][2];
  // boundary pre-reads for tile 0 (the P4(-1) reads): wlo(0) + xlo(0)
#pragma unroll
  for (int n = 0; n < 2; ++n) {
    wlo[n][0] = LDF(pB0, n * 1024);
    wlo[n][1] = LDF(pB0, n * 1024 + 8192);
  }
#pragma unroll
  for (int m = 0; m < 4; ++m) {
    xlo[m][0] = LDF(pA0, m * 1024);
    xlo[m][1] = LDF(pA0, m * 1024 + 8192);
  }

  // One K-tile. CB/NB = cur/next staging buffer; PA/PB = cur read bases;
  // PAN/PBN = next read bases; t = tile index.
#define KTILE(CB, NB, PA, PB, PAN, PBN, t)                                     \
  {                                                                            \
    /* P1: read whi(t) (4); stage A0+A1(t+1); Q0 (wlo,xlo from P4); bar */     \
    _Pragma("unroll")                                                          \
    for (int n = 0; n < 2; ++n) {                                              \
      whi[n][0] = LDF(PB, (n + 2) * 1024);                                     \
      whi[n][1] = LDF(PB, (n + 2) * 1024 + 8192);                              \
    }                                                                          \
    if ((t) + 1 < NT) { stageHalf((NB), 2, (t) + 1);                           \
                        stageHalf((NB), 3, (t) + 1); }                         \
    __builtin_amdgcn_s_setprio(1);                                             \
    _Pragma("unroll")                                                          \
    for (int kk = 0; kk < 2; ++kk)                                             \
      _Pragma("unroll")                                                        \
      for (int m = 0; m < 4; ++m)                                              \
        _Pragma("unroll")                                                      \
        for (int n = 0; n < 2; ++n)                                            \
          acc[m][n] = __builtin_amdgcn_mfma_f32_16x16x32_bf16(                 \
              wlo[n][kk], xlo[m][kk], acc[m][n], 0, 0, 0);                     \
    __builtin_amdgcn_s_setprio(0);                                             \
    __builtin_amdgcn_s_barrier();                                              \
    /* P2: read xhi(t) (8); Q1 (whi read P1); bar */                           \
    _Pragma("unroll")                                                          \
    for (int m = 0; m < 4; ++m) {                                              \
      xhi[m][0] = LDF(PA, (m + 4) * 1024);                                     \
      xhi[m][1] = LDF(PA, (m + 4) * 1024 + 8192);                              \
    }                                                                          \
    __builtin_amdgcn_s_setprio(1);                                             \
    _Pragma("unroll")                                                          \
    for (int kk = 0; kk < 2; ++kk)                                             \
      _Pragma("unroll")                                                        \
      for (int m = 0; m < 4; ++m)                                              \
        _Pragma("unroll")                                                      \
        for (int n = 0; n < 2; ++n)                                            \
          acc[m][n + 2] = __builtin_amdgcn_mfma_f32_16x16x32_bf16(             \
              whi[n][kk], xlo[m][kk], acc[m][n + 2], 0, 0, 0);                 \
    __builtin_amdgcn_s_setprio(0);                                             \
    __builtin_amdgcn_s_barrier();                                              \
    /* P3: no reads; stage B0+B1(t+2) into CB; Q2 (xhi read P2); bar */        \
    if ((t) + 2 < NT) { stageHalf((CB), 0, (t) + 2);                           \
                        stageHalf((CB), 1, (t) + 2); }                         \
    __builtin_amdgcn_s_setprio(1);                                             \
    _Pragma("unroll")                                                          \
    for (int kk = 0; kk < 2; ++kk)                                             \
      _Pragma("unroll")                                                        \
      for (int m = 0; m < 4; ++m)                                              \
        _Pragma("unroll")                                                      \
        for (int n = 0; n < 2; ++n)                                            \
          acc[m + 4][n + 2] = __builtin_amdgcn_mfma_f32_16x16x32_bf16(         \
              whi[n][kk], xhi[m][kk], acc[m + 4][n + 2], 0, 0, 0);             \
    __builtin_amdgcn_s_setprio(0);                                             \
    __builtin_amdgcn_s_barrier();                                              \
    /* P4: vmcnt(4); bar; Q3 FIRST; then boundary reads wlo+xlo(t+1) into      \
       the just-freed regs (WAR, no dbuf), draining into P1 */                 \
    if ((t) < NT - 2)       asm volatile("s_waitcnt vmcnt(4)" ::: "memory");   \
    else if ((t) == NT - 2) asm volatile("s_waitcnt vmcnt(0)" ::: "memory");   \
    __builtin_amdgcn_s_barrier();                                              \
    __builtin_amdgcn_s_setprio(1);                                             \
    _Pragma("unroll")                                                          \
    for (int kk = 0; kk < 2; ++kk)                                             \
      _Pragma("unroll")                                                        \
      for (int m = 0; m < 4; ++m)                                              \
        _Pragma("unroll")                                                      \
        for (int n = 0; n < 2; ++n)                                            \
          acc[m + 4][n] = __builtin_amdgcn_mfma_f32_16x16x32_bf16(             \
              wlo[n][kk], xhi[m][kk], acc[m + 4][n], 0, 0, 0);                 \
    __builtin_amdgcn_s_setprio(0);                                             \
    if ((t) + 1 < NT) {                                                        \
      _Pragma("unroll")                                                        \
      for (int n = 0; n < 2; ++n) {                                            \
        wlo[n][0] = LDF(PBN, n * 1024);                                        \
        wlo[n][1] = LDF(PBN, n * 1024 + 8192);                                 \
      }                                                                        \
      _Pragma("unroll")                                                        \
      for (int m = 0; m < 4; ++m) {                                            \
        xlo[m][0] = LDF(PAN, m * 1024);                                        \
        xlo[m][1] = LDF(PAN, m * 1024 + 8192);                                 \
      }                                                                        \
    }                                                                          \
  }

  for (int tt = 0; tt < NT; tt += 2) {
    KTILE(buf0, buf1, pA0, pB0, pA1, pB1, tt);
    KTILE(buf1, buf0, pA1, pB1, pA0, pB0, tt + 1);
  }
#undef KTILE

  // epilogue: swapped C/D layout -> lane holds 4 consecutive C columns:
  //   Crow = brow + wm*128 + m*16 + (lane&15),
  //   Ccol = bcol + wn*64 + n*16 + hi*4 + j  -> NONTEMPORAL dwordx4 stores
#pragma unroll
  for (int n = 0; n < 4; ++n) {
    const int colb = bcol + wn * 64 + n * 16 + hi * 4;
    const f32x4 bv = *reinterpret_cast<const f32x4*>(&bias[colb]);
#pragma unroll
    for (int m = 0; m < 8; ++m) {
      const size_t row = (size_t)brow + wm * 128 + m * 16 + r16;
      f32x4 v = acc[m][n] + bv;
      __builtin_nontemporal_store(v, reinterpret_cast<f32x4*>(&C[row * NDIM + colb]));
    }
  }
}

// ---------------------------------------------------------------------------
extern "C" void kernel_launch(void* const* d_in, const int* in_sizes, int n_in,
                              void* d_out, int out_size, void* d_ws, size_t ws_size,
                              hipStream_t stream) {
  const float* x  = (const float*)d_in[0];   // [4,4096,4096]
  const float* W  = (const float*)d_in[1];   // [4096,4096]
  const float* b  = (const float*)d_in[2];   // [4096]
  const float* lA = (const float*)d_in[3];   // [16,4096]
  const float* lB = (const float*)d_in[4];   // [4096,16]
  float* out = (float*)d_out;                // [4,4096,4096] fp32

  unsigned short* xb = (unsigned short*)d_ws;
  unsigned short* Wp = (unsigned short*)((char*)d_ws + (size_t)MDIM * KDIM * 2);

  fused_prep_kernel<<<4096, 256, 0, stream>>>(x, W, lA, lB, xb, Wp);
  gemm256_kernel<<<1024, 512, 0, stream>>>(xb, Wp, b, out);
}